// Round 3
// baseline (2964.342 us; speedup 1.0000x reference)
//
#include <hip/hip_runtime.h>
#include <math.h>

#define NLEV 12
#define B_LINES 4096
#define P_PTS 1000

// Per-level table layout, mirrors _level_specs() exactly (computed host-side
// with the same double-precision pow/ceil arithmetic as numpy).
struct LevelSpec {
    unsigned off;    // entry offset into table ([T,2] rows)
    unsigned mask;   // params-1 (power-of-2 for hash levels; unused for dense)
    float    scale;  // BASE_RES * f^l - 1
    unsigned R;      // res + 1 (dense stride base)
};
struct Specs { LevelSpec L[NLEV]; };

static void compute_specs(int D, Specs* sp) {
    double f = pow(8192.0 / 16.0, 1.0 / 11.0);
    unsigned offset = 0;
    for (int l = 0; l < NLEV; ++l) {
        double scale = 16.0 * pow(f, (double)l) - 1.0;
        int res = (int)ceil(scale) + 1;
        unsigned long long dense = 1ull;
        for (int d = 0; d < D; ++d) dense *= (unsigned long long)(res + 1);
        unsigned long long params = dense > (1ull << 21) ? (1ull << 21) : dense;
        params = ((params + 7ull) / 8ull) * 8ull;
        sp->L[l].off   = offset;
        sp->L[l].mask  = (unsigned)params - 1u;
        sp->L[l].scale = (float)scale;
        sp->L[l].R     = (unsigned)(res + 1);
        offset += (unsigned)params;
    }
}

// ---------------------------------------------------------------------------

__device__ __forceinline__ float block_reduce_256(float v) {
    __shared__ float red[256];
    int tid = threadIdx.x;
    red[tid] = v;
    __syncthreads();
    #pragma unroll
    for (int s = 128; s >= 1; s >>= 1) {
        if (tid < s) red[tid] += red[tid + s];
        __syncthreads();
    }
    return red[0];
}

// MLP 24 -> 64(relu) -> 1. Weights are wave-uniform -> backend scalarizes to
// s_load; inner loop is v_fmac with SGPR operand. h in two 32-reg halves.
__device__ __forceinline__ float mlp_24_64_1(const float feat[24],
        const float* __restrict__ w1, const float* __restrict__ b1,
        const float* __restrict__ w2, const float* __restrict__ b2) {
    float o = b2[0];
    #pragma unroll
    for (int half = 0; half < 2; ++half) {
        float h[32];
        #pragma unroll
        for (int j = 0; j < 32; ++j) h[j] = b1[half * 32 + j];
        #pragma unroll
        for (int k = 0; k < 24; ++k) {
            float fv = feat[k];
            #pragma unroll
            for (int j = 0; j < 32; ++j)
                h[j] = fmaf(fv, w1[k * 64 + half * 32 + j], h[j]);
        }
        #pragma unroll
        for (int j = 0; j < 32; ++j)
            o = fmaf(fmaxf(h[j], 0.f), w2[half * 32 + j], o);
    }
    return o;
}

// Encode a batch of 2 levels: all 16 gathers issued into t[] before any
// consumption. Batch size 2 (32 dest VGPRs) chosen so the whole kernel fits
// in 128 VGPRs -> 4 waves/SIMD with __launch_bounds__(256,4): the point of
// R3 is maximizing (resident waves) x (loads in flight per wave).
template<int L0, bool HASH>
__device__ __forceinline__ void enc_batch2(float x0, float x1, float x2,
        const float2* __restrict__ tab, const Specs& sp,
        float* __restrict__ feat) {
    float r[2][3];
    float2 t[16];
    #pragma unroll
    for (int j = 0; j < 2; ++j) {
        const LevelSpec& L = sp.L[L0 + j];
        float p0 = x0 * L.scale + 0.5f;
        float p1 = x1 * L.scale + 0.5f;
        float p2 = x2 * L.scale + 0.5f;
        float f0 = floorf(p0), f1 = floorf(p1), f2 = floorf(p2);
        r[j][0] = p0 - f0; r[j][1] = p1 - f1; r[j][2] = p2 - f2;
        unsigned g0 = (unsigned)f0, g1 = (unsigned)f1, g2 = (unsigned)f2;
        const float2* __restrict__ base = tab + L.off;
        if (HASH) {
            unsigned y0 = g1 * 2654435761u, y1 = y0 + 2654435761u;
            unsigned z0 = g2 * 805459861u,  z1 = z0 + 805459861u;
            unsigned m = L.mask;
            #pragma unroll
            for (int c = 0; c < 8; ++c) {
                unsigned h = (g0 + ((c & 1) ? 1u : 0u))
                           ^ ((c & 2) ? y1 : y0)
                           ^ ((c & 4) ? z1 : z0);
                t[8 * j + c] = base[h & m];
            }
        } else {
            unsigned R = L.R, R2 = R * R;
            unsigned y0 = g1 * R, y1 = y0 + R;
            unsigned z0 = g2 * R2, z1 = z0 + R2;
            #pragma unroll
            for (int c = 0; c < 8; ++c) {
                unsigned idx = (g0 + ((c & 1) ? 1u : 0u))
                             + ((c & 2) ? y1 : y0)
                             + ((c & 4) ? z1 : z0);
                t[8 * j + c] = base[idx];
            }
        }
    }
    #pragma unroll
    for (int j = 0; j < 2; ++j) {
        float r0 = r[j][0], r1 = r[j][1], r2 = r[j][2];
        float u0 = 1.f - r0, u1 = 1.f - r1, u2 = 1.f - r2;
        float a0 = 0.f, a1 = 0.f;
        #pragma unroll
        for (int c = 0; c < 8; ++c) {
            float w = ((c & 1) ? r0 : u0) * ((c & 2) ? r1 : u1)
                    * ((c & 4) ? r2 : u2);
            a0 = fmaf(w, t[8 * j + c].x, a0);
            a1 = fmaf(w, t[8 * j + c].y, a1);
        }
        feat[2 * (L0 + j)]     = a0;
        feat[2 * (L0 + j) + 1] = a1;
    }
}

// ---------------------------------------------------------------------------
// Kernel A: one block per line; per-line weighted sum of |opacity - gt|.
// __launch_bounds__(256,4): force VGPR<=128 so 4 waves/SIMD (16 waves/CU)
// stay resident — R3 discriminating experiment for the concurrency wall.
__global__ void __launch_bounds__(256, 4) opacity_kernel(
        const float* __restrict__ pts,      // [B*P, 3]
        const float* __restrict__ gt,       // [B*P]
        const float2* __restrict__ tab,     // [tot3, 2]
        const float* __restrict__ w1, const float* __restrict__ b1,
        const float* __restrict__ w2, const float* __restrict__ b2,
        float* __restrict__ S,              // [B] per-line sums
        Specs sp) {
    const int b = blockIdx.x;
    const int tid = threadIdx.x;
    float lsum = 0.f;
    for (int p = tid; p < P_PTS; p += 256) {
        const int i = b * P_PTS + p;
        float x0 = (pts[3 * i + 0] + 1.f) * 0.5f;
        float x1 = (pts[3 * i + 1] + 1.f) * 0.5f;
        float x2 = (pts[3 * i + 2] + 1.f) * 0.5f;
        float g = gt[i];
        float feat[24];
        enc_batch2<0,  false>(x0, x1, x2, tab, sp, feat);  // dense 0-1
        enc_batch2<2,  false>(x0, x1, x2, tab, sp, feat);  // dense 2-3
        enc_batch2<4,  true >(x0, x1, x2, tab, sp, feat);  // hash 4-5
        enc_batch2<6,  true >(x0, x1, x2, tab, sp, feat);  // hash 6-7
        enc_batch2<8,  true >(x0, x1, x2, tab, sp, feat);  // hash 8-9
        enc_batch2<10, true >(x0, x1, x2, tab, sp, feat);  // hash 10-11
        float op = mlp_24_64_1(feat, w1, b1, w2, b2);
        float cw = (p < 500) ? (float)(4.0 / 3.0) : (float)(2.0 / 3.0);
        lsum += fabsf(op - g) * cw;
    }
    float tot = block_reduce_256(lsum);
    if (tid == 0) S[b] = tot;
}

// Kernel B: one thread per line -> confidence + loss term; per-block partials.
__global__ void __launch_bounds__(256) conf_kernel(
        const float* __restrict__ line,     // [B, 2]
        const float2* __restrict__ tab,     // [tot2, 2]
        const float* __restrict__ w1, const float* __restrict__ b1,
        const float* __restrict__ w2, const float* __restrict__ b2,
        const float* __restrict__ S,        // [B]
        float* __restrict__ partial,        // [16]
        Specs sp) {
    const int b = blockIdx.x * 256 + threadIdx.x;   // grid 16*256 == 4096 exact
    float x0 = (line[2 * b + 0] + 1.f) * 0.5f;
    float x1 = (line[2 * b + 1] + 1.f) * 0.5f;
    float feat[24];
    #pragma unroll
    for (int l = 0; l < NLEV; ++l) {
        const unsigned off = sp.L[l].off;
        const float scale = sp.L[l].scale;
        float p0 = x0 * scale + 0.5f;
        float p1 = x1 * scale + 0.5f;
        float f0 = floorf(p0), f1 = floorf(p1);
        float r0 = p0 - f0, r1 = p1 - f1;
        float u0 = 1.f - r0, u1 = 1.f - r1;
        unsigned g0 = (unsigned)f0, g1 = (unsigned)f1;
        unsigned idx0, idx1, idx2, idx3;
        if (l >= 8) {  // hash levels for D=2 ((res+1)^2 > 2^21 from l=8)
            const unsigned mask = sp.L[l].mask;
            unsigned a1 = g1 * 2654435761u, bb1 = a1 + 2654435761u;
            idx0 = (g0 ^ a1) & mask;
            idx1 = ((g0 + 1u) ^ a1) & mask;
            idx2 = (g0 ^ bb1) & mask;
            idx3 = ((g0 + 1u) ^ bb1) & mask;
        } else {
            const unsigned R = sp.L[l].R;
            unsigned a1 = g1 * R, bb1 = a1 + R;
            idx0 = g0 + a1;
            idx1 = g0 + 1u + a1;
            idx2 = g0 + bb1;
            idx3 = g0 + 1u + bb1;
        }
        float2 t0 = tab[off + idx0], t1 = tab[off + idx1];
        float2 t2 = tab[off + idx2], t3 = tab[off + idx3];
        float w0 = u0 * u1, w1c = r0 * u1, w2c = u0 * r1, w3 = r0 * r1;
        feat[2 * l]     = w0 * t0.x + w1c * t1.x + w2c * t2.x + w3 * t3.x;
        feat[2 * l + 1] = w0 * t0.y + w1c * t1.y + w2c * t2.y + w3 * t3.y;
    }
    float conf = mlp_24_64_1(feat, w1, b1, w2, b2);
    float term = expf(-conf) * (S[b] * (1.0f / (float)P_PTS)) + conf;
    float tot = block_reduce_256(term);
    if (threadIdx.x == 0) partial[blockIdx.x] = tot;
}

__global__ void final_kernel(const float* __restrict__ partial,
                             float* __restrict__ out) {
    if (threadIdx.x == 0) {
        float s = 0.f;
        for (int i = 0; i < 16; ++i) s += partial[i];
        out[0] = s * (1.0f / (float)B_LINES);
    }
}

// ---------------------------------------------------------------------------

extern "C" void kernel_launch(void* const* d_in, const int* in_sizes, int n_in,
                              void* d_out, int out_size, void* d_ws, size_t ws_size,
                              hipStream_t stream) {
    const float* line    = (const float*)d_in[0];
    const float* pts     = (const float*)d_in[1];
    const float* gt      = (const float*)d_in[2];
    const float* table_c = (const float*)d_in[3];
    const float* w1_c    = (const float*)d_in[4];
    const float* b1_c    = (const float*)d_in[5];
    const float* w2_c    = (const float*)d_in[6];
    const float* b2_c    = (const float*)d_in[7];
    const float* table_o = (const float*)d_in[8];
    const float* w1_o    = (const float*)d_in[9];
    const float* b1_o    = (const float*)d_in[10];
    const float* w2_o    = (const float*)d_in[11];
    const float* b2_o    = (const float*)d_in[12];
    (void)in_sizes; (void)n_in; (void)out_size; (void)ws_size;

    Specs sp3, sp2;
    compute_specs(3, &sp3);
    compute_specs(2, &sp2);

    float* S       = (float*)d_ws;       // [4096]
    float* partial = S + B_LINES;        // [16]

    opacity_kernel<<<B_LINES, 256, 0, stream>>>(
        pts, gt, (const float2*)table_o, w1_o, b1_o, w2_o, b2_o, S, sp3);
    conf_kernel<<<16, 256, 0, stream>>>(
        line, (const float2*)table_c, w1_c, b1_c, w2_c, b2_c, S, partial, sp2);
    final_kernel<<<1, 64, 0, stream>>>(partial, (float*)d_out);
}

// Round 4
// 1974.033 us; speedup vs baseline: 1.5017x; 1.5017x over previous
//
#include <hip/hip_runtime.h>
#include <hip/hip_bf16.h>
#include <math.h>

#define NLEV 12
#define B_LINES 4096
#define P_PTS 1000
#define FP8_SCALE 65536.0f
#define FP8_ISCALE (1.0f / 65536.0f)

typedef unsigned short ushort_t;

// Per-level table layout, mirrors _level_specs() exactly.
struct LevelSpec {
    unsigned off;    // entry offset into table (rows of 2 features)
    unsigned mask;   // params-1 (power-of-2 for hash levels)
    float    scale;  // BASE_RES * f^l - 1
    unsigned R;      // res + 1 (dense stride base)
};
struct Specs { LevelSpec L[NLEV]; };

static unsigned compute_specs(int D, Specs* sp) {
    double f = pow(8192.0 / 16.0, 1.0 / 11.0);
    unsigned offset = 0;
    for (int l = 0; l < NLEV; ++l) {
        double scale = 16.0 * pow(f, (double)l) - 1.0;
        int res = (int)ceil(scale) + 1;
        unsigned long long dense = 1ull;
        for (int d = 0; d < D; ++d) dense *= (unsigned long long)(res + 1);
        unsigned long long params = dense > (1ull << 21) ? (1ull << 21) : dense;
        params = ((params + 7ull) / 8ull) * 8ull;
        sp->L[l].off   = offset;
        sp->L[l].mask  = (unsigned)params - 1u;
        sp->L[l].scale = (float)scale;
        sp->L[l].R     = (unsigned)(res + 1);
        offset += (unsigned)params;
    }
    return offset;  // total entries
}

// ---------------------------------------------------------------------------

__device__ __forceinline__ float block_reduce_256(float v) {
    __shared__ float red[256];
    int tid = threadIdx.x;
    red[tid] = v;
    __syncthreads();
    #pragma unroll
    for (int s = 128; s >= 1; s >>= 1) {
        if (tid < s) red[tid] += red[tid + s];
        __syncthreads();
    }
    return red[0];
}

// MLP 24 -> 64(relu) -> 1; weights wave-uniform -> s_load + v_fmac.
__device__ __forceinline__ float mlp_24_64_1(const float feat[24],
        const float* __restrict__ w1, const float* __restrict__ b1,
        const float* __restrict__ w2, const float* __restrict__ b2) {
    float o = b2[0];
    #pragma unroll
    for (int half = 0; half < 2; ++half) {
        float h[32];
        #pragma unroll
        for (int j = 0; j < 32; ++j) h[j] = b1[half * 32 + j];
        #pragma unroll
        for (int k = 0; k < 24; ++k) {
            float fv = feat[k];
            #pragma unroll
            for (int j = 0; j < 32; ++j)
                h[j] = fmaf(fv, w1[k * 64 + half * 32 + j], h[j]);
        }
        #pragma unroll
        for (int j = 0; j < 32; ++j)
            o = fmaf(fmaxf(h[j], 0.f), w2[half * 32 + j], o);
    }
    return o;
}

// ---------------------------------------------------------------------------
// fp8 table conversion: one row (2 features) -> 2 bytes, scaled by 2^16.
__global__ void __launch_bounds__(256) convert_kernel(
        const float2* __restrict__ in, ushort_t* __restrict__ out, int n) {
    int i = blockIdx.x * 256 + threadIdx.x;
    if (i >= n) return;
    float2 v = in[i];
    int p = __builtin_amdgcn_cvt_pk_fp8_f32(v.x * FP8_SCALE, v.y * FP8_SCALE,
                                            0, false);
    out[i] = (ushort_t)(p & 0xffff);
}

// Dense levels 0..3 (combined fp8 footprint ~1.8 MB: L2-resident).
__global__ void __launch_bounds__(256) enc_dense_kernel(
        const float* __restrict__ pts, int pbase, int npts,
        const ushort_t* __restrict__ tabq,
        __hip_bfloat162* __restrict__ feats,   // 12 slabs of npts
        Specs sp) {
    int i = blockIdx.x * 256 + threadIdx.x;
    if (i >= npts) return;
    int gp = pbase + i;
    float x0 = (pts[3 * gp + 0] + 1.f) * 0.5f;
    float x1 = (pts[3 * gp + 1] + 1.f) * 0.5f;
    float x2 = (pts[3 * gp + 2] + 1.f) * 0.5f;
    #pragma unroll
    for (int l = 0; l < 4; ++l) {
        const LevelSpec L = sp.L[l];
        float p0 = x0 * L.scale + 0.5f;
        float p1 = x1 * L.scale + 0.5f;
        float p2 = x2 * L.scale + 0.5f;
        float f0 = floorf(p0), f1 = floorf(p1), f2 = floorf(p2);
        float r0 = p0 - f0, r1 = p1 - f1, r2 = p2 - f2;
        float u0 = 1.f - r0, u1 = 1.f - r1, u2 = 1.f - r2;
        unsigned g0 = (unsigned)f0, g1 = (unsigned)f1, g2 = (unsigned)f2;
        const ushort_t* __restrict__ base = tabq + L.off;
        unsigned R = L.R, R2 = R * R;
        unsigned y0 = g1 * R, y1 = y0 + R;
        unsigned z0 = g2 * R2, z1 = z0 + R2;
        int t[8];
        #pragma unroll
        for (int c = 0; c < 8; ++c) {
            unsigned idx = (g0 + ((c & 1) ? 1u : 0u))
                         + ((c & 2) ? y1 : y0) + ((c & 4) ? z1 : z0);
            t[c] = (int)base[idx];
        }
        float a0 = 0.f, a1 = 0.f;
        #pragma unroll
        for (int c = 0; c < 8; ++c) {
            float w = ((c & 1) ? r0 : u0) * ((c & 2) ? r1 : u1)
                    * ((c & 4) ? r2 : u2);
            a0 = fmaf(w, __builtin_amdgcn_cvt_f32_fp8(t[c], 0), a0);
            a1 = fmaf(w, __builtin_amdgcn_cvt_f32_fp8(t[c], 1), a1);
        }
        __hip_bfloat162 o;
        o.x = __float2bfloat16(a0 * FP8_ISCALE);
        o.y = __float2bfloat16(a1 * FP8_ISCALE);
        feats[(size_t)l * npts + i] = o;
    }
}

// One hash level per launch: the 4 MB fp8 level table fits each XCD's L2.
__global__ void __launch_bounds__(256) enc_hash_kernel(
        const float* __restrict__ pts, int pbase, int npts,
        const ushort_t* __restrict__ tabq, LevelSpec L,
        __hip_bfloat162* __restrict__ featsl) {   // this level's slab
    int i = blockIdx.x * 256 + threadIdx.x;
    if (i >= npts) return;
    int gp = pbase + i;
    float x0 = (pts[3 * gp + 0] + 1.f) * 0.5f;
    float x1 = (pts[3 * gp + 1] + 1.f) * 0.5f;
    float x2 = (pts[3 * gp + 2] + 1.f) * 0.5f;
    float p0 = x0 * L.scale + 0.5f;
    float p1 = x1 * L.scale + 0.5f;
    float p2 = x2 * L.scale + 0.5f;
    float f0 = floorf(p0), f1 = floorf(p1), f2 = floorf(p2);
    float r0 = p0 - f0, r1 = p1 - f1, r2 = p2 - f2;
    float u0 = 1.f - r0, u1 = 1.f - r1, u2 = 1.f - r2;
    unsigned g0 = (unsigned)f0, g1 = (unsigned)f1, g2 = (unsigned)f2;
    const ushort_t* __restrict__ base = tabq + L.off;
    unsigned y0 = g1 * 2654435761u, y1 = y0 + 2654435761u;
    unsigned z0 = g2 * 805459861u,  z1 = z0 + 805459861u;
    unsigned m = L.mask;
    int t[8];
    #pragma unroll
    for (int c = 0; c < 8; ++c) {
        unsigned h = (g0 + ((c & 1) ? 1u : 0u))
                   ^ ((c & 2) ? y1 : y0) ^ ((c & 4) ? z1 : z0);
        t[c] = (int)base[h & m];
    }
    float a0 = 0.f, a1 = 0.f;
    #pragma unroll
    for (int c = 0; c < 8; ++c) {
        float w = ((c & 1) ? r0 : u0) * ((c & 2) ? r1 : u1)
                * ((c & 4) ? r2 : u2);
        a0 = fmaf(w, __builtin_amdgcn_cvt_f32_fp8(t[c], 0), a0);
        a1 = fmaf(w, __builtin_amdgcn_cvt_f32_fp8(t[c], 1), a1);
    }
    __hip_bfloat162 o;
    o.x = __float2bfloat16(a0 * FP8_ISCALE);
    o.y = __float2bfloat16(a1 * FP8_ISCALE);
    featsl[i] = o;
}

// Per-line MLP + weighted |op-gt| sum. One block per line.
__global__ void __launch_bounds__(256) mlp_loss_kernel(
        const __hip_bfloat162* __restrict__ feats, int npts,
        const float* __restrict__ gt, int line0,
        const float* __restrict__ w1, const float* __restrict__ b1,
        const float* __restrict__ w2, const float* __restrict__ b2,
        float* __restrict__ S) {
    const int line_local = blockIdx.x;
    const int line = line0 + line_local;
    const int tid = threadIdx.x;
    float lsum = 0.f;
    for (int p = tid; p < P_PTS; p += 256) {
        size_t local = (size_t)line_local * P_PTS + p;
        float feat[24];
        #pragma unroll
        for (int l = 0; l < NLEV; ++l) {
            __hip_bfloat162 v = feats[(size_t)l * npts + local];
            feat[2 * l]     = __bfloat162float(v.x);
            feat[2 * l + 1] = __bfloat162float(v.y);
        }
        float op = mlp_24_64_1(feat, w1, b1, w2, b2);
        float g = gt[(size_t)line * P_PTS + p];
        float cw = (p < 500) ? (float)(4.0 / 3.0) : (float)(2.0 / 3.0);
        lsum += fabsf(op - g) * cw;
    }
    float tot = block_reduce_256(lsum);
    if (tid == 0) S[line] = tot;
}

// ---------------------------------------------------------------------------
// Fallback monolithic opacity kernel (R1 structure) if ws is too small.
__global__ void __launch_bounds__(256) opacity_mono_kernel(
        const float* __restrict__ pts, const float* __restrict__ gt,
        const float2* __restrict__ tab,
        const float* __restrict__ w1, const float* __restrict__ b1,
        const float* __restrict__ w2, const float* __restrict__ b2,
        float* __restrict__ S, Specs sp) {
    const int b = blockIdx.x;
    const int tid = threadIdx.x;
    float lsum = 0.f;
    for (int p = tid; p < P_PTS; p += 256) {
        const int i = b * P_PTS + p;
        float x0 = (pts[3 * i + 0] + 1.f) * 0.5f;
        float x1 = (pts[3 * i + 1] + 1.f) * 0.5f;
        float x2 = (pts[3 * i + 2] + 1.f) * 0.5f;
        float feat[24];
        #pragma unroll
        for (int l = 0; l < NLEV; ++l) {
            const LevelSpec L = sp.L[l];
            float p0 = x0 * L.scale + 0.5f;
            float p1 = x1 * L.scale + 0.5f;
            float p2 = x2 * L.scale + 0.5f;
            float f0 = floorf(p0), f1 = floorf(p1), f2 = floorf(p2);
            float r0 = p0 - f0, r1 = p1 - f1, r2 = p2 - f2;
            float u0 = 1.f - r0, u1 = 1.f - r1, u2 = 1.f - r2;
            unsigned g0 = (unsigned)f0, g1 = (unsigned)f1, g2 = (unsigned)f2;
            float a0 = 0.f, a1 = 0.f;
            if (l >= 4) {
                unsigned y0 = g1 * 2654435761u, y1 = y0 + 2654435761u;
                unsigned z0 = g2 * 805459861u,  z1 = z0 + 805459861u;
                unsigned m = L.mask;
                #pragma unroll
                for (int c = 0; c < 8; ++c) {
                    unsigned h = (g0 + ((c & 1) ? 1u : 0u))
                               ^ ((c & 2) ? y1 : y0) ^ ((c & 4) ? z1 : z0);
                    float2 t = tab[L.off + (h & m)];
                    float w = ((c & 1) ? r0 : u0) * ((c & 2) ? r1 : u1)
                            * ((c & 4) ? r2 : u2);
                    a0 = fmaf(w, t.x, a0); a1 = fmaf(w, t.y, a1);
                }
            } else {
                unsigned R = L.R, R2 = R * R;
                unsigned y0 = g1 * R, y1 = y0 + R;
                unsigned z0 = g2 * R2, z1 = z0 + R2;
                #pragma unroll
                for (int c = 0; c < 8; ++c) {
                    unsigned idx = (g0 + ((c & 1) ? 1u : 0u))
                                 + ((c & 2) ? y1 : y0) + ((c & 4) ? z1 : z0);
                    float2 t = tab[L.off + idx];
                    float w = ((c & 1) ? r0 : u0) * ((c & 2) ? r1 : u1)
                            * ((c & 4) ? r2 : u2);
                    a0 = fmaf(w, t.x, a0); a1 = fmaf(w, t.y, a1);
                }
            }
            feat[2 * l] = a0; feat[2 * l + 1] = a1;
        }
        float op = mlp_24_64_1(feat, w1, b1, w2, b2);
        float cw = (p < 500) ? (float)(4.0 / 3.0) : (float)(2.0 / 3.0);
        lsum += fabsf(op - gt[i]) * cw;
    }
    float tot = block_reduce_256(lsum);
    if (tid == 0) S[b] = tot;
}

// Confidence (D=2, tiny) + final reduction: unchanged from R1 (f32 table).
__global__ void __launch_bounds__(256) conf_kernel(
        const float* __restrict__ line, const float2* __restrict__ tab,
        const float* __restrict__ w1, const float* __restrict__ b1,
        const float* __restrict__ w2, const float* __restrict__ b2,
        const float* __restrict__ S, float* __restrict__ partial, Specs sp) {
    const int b = blockIdx.x * 256 + threadIdx.x;
    float x0 = (line[2 * b + 0] + 1.f) * 0.5f;
    float x1 = (line[2 * b + 1] + 1.f) * 0.5f;
    float feat[24];
    #pragma unroll
    for (int l = 0; l < NLEV; ++l) {
        const unsigned off = sp.L[l].off;
        const float scale = sp.L[l].scale;
        float p0 = x0 * scale + 0.5f;
        float p1 = x1 * scale + 0.5f;
        float f0 = floorf(p0), f1 = floorf(p1);
        float r0 = p0 - f0, r1 = p1 - f1;
        float u0 = 1.f - r0, u1 = 1.f - r1;
        unsigned g0 = (unsigned)f0, g1 = (unsigned)f1;
        unsigned idx0, idx1, idx2, idx3;
        if (l >= 8) {
            const unsigned mask = sp.L[l].mask;
            unsigned a1 = g1 * 2654435761u, bb1 = a1 + 2654435761u;
            idx0 = (g0 ^ a1) & mask;
            idx1 = ((g0 + 1u) ^ a1) & mask;
            idx2 = (g0 ^ bb1) & mask;
            idx3 = ((g0 + 1u) ^ bb1) & mask;
        } else {
            const unsigned R = sp.L[l].R;
            unsigned a1 = g1 * R, bb1 = a1 + R;
            idx0 = g0 + a1; idx1 = g0 + 1u + a1;
            idx2 = g0 + bb1; idx3 = g0 + 1u + bb1;
        }
        float2 t0 = tab[off + idx0], t1 = tab[off + idx1];
        float2 t2 = tab[off + idx2], t3 = tab[off + idx3];
        float w0 = u0 * u1, w1c = r0 * u1, w2c = u0 * r1, w3 = r0 * r1;
        feat[2 * l]     = w0 * t0.x + w1c * t1.x + w2c * t2.x + w3 * t3.x;
        feat[2 * l + 1] = w0 * t0.y + w1c * t1.y + w2c * t2.y + w3 * t3.y;
    }
    float conf = mlp_24_64_1(feat, w1, b1, w2, b2);
    float term = expf(-conf) * (S[b] * (1.0f / (float)P_PTS)) + conf;
    float tot = block_reduce_256(term);
    if (threadIdx.x == 0) partial[blockIdx.x] = tot;
}

__global__ void final_kernel(const float* __restrict__ partial,
                             float* __restrict__ out) {
    if (threadIdx.x == 0) {
        float s = 0.f;
        for (int i = 0; i < 16; ++i) s += partial[i];
        out[0] = s * (1.0f / (float)B_LINES);
    }
}

// ---------------------------------------------------------------------------

extern "C" void kernel_launch(void* const* d_in, const int* in_sizes, int n_in,
                              void* d_out, int out_size, void* d_ws, size_t ws_size,
                              hipStream_t stream) {
    const float* line    = (const float*)d_in[0];
    const float* pts     = (const float*)d_in[1];
    const float* gt      = (const float*)d_in[2];
    const float* table_c = (const float*)d_in[3];
    const float* w1_c    = (const float*)d_in[4];
    const float* b1_c    = (const float*)d_in[5];
    const float* w2_c    = (const float*)d_in[6];
    const float* b2_c    = (const float*)d_in[7];
    const float* table_o = (const float*)d_in[8];
    const float* w1_o    = (const float*)d_in[9];
    const float* b1_o    = (const float*)d_in[10];
    const float* w2_o    = (const float*)d_in[11];
    const float* b2_o    = (const float*)d_in[12];
    (void)in_sizes; (void)n_in; (void)out_size;

    Specs sp3, sp2;
    unsigned tot3 = compute_specs(3, &sp3);
    compute_specs(2, &sp2);

    // ws layout: [fp8 table][S 4096][partial 16][feat slabs]
    size_t tabB = (((size_t)tot3 * 2) + 255) & ~(size_t)255;
    size_t head = tabB + (size_t)B_LINES * 4 + 64;
    head = (head + 63) & ~(size_t)63;
    long max_lines = 0;
    if (ws_size > head + 64)
        max_lines = (long)((ws_size - head - 64) / ((size_t)P_PTS * 12 * 4));

    float* S       = (float*)((char*)d_ws + tabB);
    float* partial = S + B_LINES;

    if (max_lines >= 64) {
        // Phased fp8 path.
        ushort_t* tabq = (ushort_t*)d_ws;
        __hip_bfloat162* featbuf = (__hip_bfloat162*)((char*)d_ws + head);

        int chunk_lines = (int)(max_lines < B_LINES ? max_lines : B_LINES);
        int nch = (B_LINES + chunk_lines - 1) / chunk_lines;

        convert_kernel<<<((int)tot3 + 255) / 256, 256, 0, stream>>>(
            (const float2*)table_o, tabq, (int)tot3);

        for (int ch = 0; ch < nch; ++ch) {
            int line0 = ch * chunk_lines;
            int lines = B_LINES - line0 < chunk_lines ? B_LINES - line0
                                                      : chunk_lines;
            int npts = lines * P_PTS;
            int pbase = line0 * P_PTS;
            int grid = (npts + 255) / 256;
            enc_dense_kernel<<<grid, 256, 0, stream>>>(
                pts, pbase, npts, tabq, featbuf, sp3);
            for (int l = 4; l < NLEV; ++l)
                enc_hash_kernel<<<grid, 256, 0, stream>>>(
                    pts, pbase, npts, tabq, sp3.L[l],
                    featbuf + (size_t)l * npts);
            mlp_loss_kernel<<<lines, 256, 0, stream>>>(
                featbuf, npts, gt, line0, w1_o, b1_o, w2_o, b2_o, S);
        }
    } else {
        // Fallback: monolithic f32 path (needs only S+partial in ws).
        opacity_mono_kernel<<<B_LINES, 256, 0, stream>>>(
            pts, gt, (const float2*)table_o, w1_o, b1_o, w2_o, b2_o, S, sp3);
    }

    conf_kernel<<<16, 256, 0, stream>>>(
        line, (const float2*)table_c, w1_c, b1_c, w2_c, b2_c, S, partial, sp2);
    final_kernel<<<1, 64, 0, stream>>>(partial, (float*)d_out);
}